// Round 9
// baseline (288.385 us; speedup 1.0000x reference)
//
#include <hip/hip_runtime.h>
#include <hip/hip_bf16.h>

typedef __attribute__((ext_vector_type(8))) __bf16 bf16x8;
typedef __attribute__((ext_vector_type(4))) float floatx4;
typedef __attribute__((ext_vector_type(2))) float floatx2;
typedef __attribute__((ext_vector_type(4))) int intx4;
typedef __attribute__((ext_vector_type(2))) unsigned uintx2;

constexpr int N_NODES = 100000;
constexpr int P_PERM  = 200000;

// ws layout (bytes)
constexpr size_t W2F_OFF  = 0;          // [16][2][4][64][8] bf16 = 131072 B (8192 B per a)
constexpr size_t WLF_OFF  = 131072;     // [2][4][64][8]  bf16 = 8192 B
constexpr size_t WD1F_OFF = 139264;     // [4][4][64][8]  bf16 = 16384 B
constexpr size_t BE_OFF   = 155648;     // [P*16] u8 packed = 3.2e6 B
constexpr size_t NF8_OFF  = 3355648;    // [100000][64] fp8 e4m3 = 6.4e6 B
constexpr size_t WS_NEED_FULL = 3355648 + (size_t)N_NODES * 64;

// HW fp8 e4m3 (OCP on gfx950) pack/unpack
__device__ inline unsigned pack_fp8x4(float x0, float x1, float x2, float x3) {
  int w = __builtin_amdgcn_cvt_pk_fp8_f32(x0, x1, 0, false);
  w = __builtin_amdgcn_cvt_pk_fp8_f32(x2, x3, w, true);
  return (unsigned)w;
}
__device__ inline floatx2 unpk_fp8_lo(unsigned w) {
  return __builtin_amdgcn_cvt_pk_f32_fp8((int)w, false);
}
__device__ inline floatx2 unpk_fp8_hi(unsigned w) {
  return __builtin_amdgcn_cvt_pk_f32_fp8((int)w, true);
}

// ---- out zeroing as a kernel (R6-verified path; memset node was suspect) ----
__global__ void zero_out_kernel(float4* __restrict__ out) {
  out[blockIdx.x * 256 + threadIdx.x] = make_float4(0.f, 0.f, 0.f, 0.f);
}

// ---- lean prep (R8): 6554 blocks ----
__global__ void prep_all_kernel(const float* __restrict__ weights,
                                const float* __restrict__ w_lin,
                                const float* __restrict__ w_deg1,
                                const float* __restrict__ nfeat,
                                const int* __restrict__ e2p_col,
                                const int* __restrict__ edge_feat_idx,
                                __bf16* __restrict__ ws_bf) {
  int b = blockIdx.x;
  int t = threadIdx.x;
  if (b < 304) {
    int i = b * 256 + t;
    if (i < 65536) {
      int j = i & 7, l = (i >> 3) & 63, ct = (i >> 9) & 3, ks = (i >> 11) & 1, a = i >> 12;
      int k = ks * 32 + (l >> 4) * 8 + j;
      int c = ct * 16 + (l & 15);
      ws_bf[W2F_OFF / 2 + i] = (__bf16)weights[k * 1024 + c * 16 + a];
    } else if (i < 65536 + 4096) {
      int i2 = i - 65536;
      int j = i2 & 7, l = (i2 >> 3) & 63, ct = (i2 >> 9) & 3, ks = (i2 >> 11) & 1;
      int k = ks * 32 + (l >> 4) * 8 + j;
      int c = ct * 16 + (l & 15);
      ws_bf[WLF_OFF / 2 + i2] = (__bf16)w_lin[c * 64 + k];
    } else if (i < 65536 + 4096 + 8192) {
      int i3 = i - 65536 - 4096;
      int j = i3 & 7, l = (i3 >> 3) & 63, ct = (i3 >> 9) & 3, ks = (i3 >> 11) & 3;
      int k = ks * 32 + (l >> 4) * 8 + j;
      int c = ct * 16 + (l & 15);
      ws_bf[WD1F_OFF / 2 + i3] = (__bf16)w_deg1[c * 128 + k];
    }
  } else if (b < 3429) {
    int i = (b - 304) * 256 + t;
    if (i < N_NODES * 8) {
      float4 a = *(const float4*)(nfeat + (size_t)i * 8);
      float4 c = *(const float4*)(nfeat + (size_t)i * 8 + 4);
      uintx2 o;
      o.x = pack_fp8x4(a.x, a.y, a.z, a.w);
      o.y = pack_fp8x4(c.x, c.y, c.z, c.w);
      *(uintx2*)((char*)ws_bf + NF8_OFF + (size_t)i * 8) = o;
    }
  } else {
    int i = (b - 3429) * 256 + t;
    if (i < P_PERM * 4) {
      int4 ec = ((const int4*)e2p_col)[i];
      unsigned v = (unsigned)(edge_feat_idx[ec.x] & 0xff)
                 | ((unsigned)(edge_feat_idx[ec.y] & 0xff) << 8)
                 | ((unsigned)(edge_feat_idx[ec.z] & 0xff) << 16)
                 | ((unsigned)(edge_feat_idx[ec.w] & 0xff) << 24);
      ((unsigned*)((char*)ws_bf + BE_OFF))[i] = v;
    }
  }
}

template <bool BF16FEAT>
__global__ __launch_bounds__(512, 4) void lrp_mfma_kernel(
    const float* __restrict__ nfeat,
    const float* __restrict__ degs,
    const float* __restrict__ n2p_val,
    const float* __restrict__ e2p_val,
    const float* __restrict__ pool_val,
    const float* __restrict__ bias,
    const float* __restrict__ w_deg0,
    const float* __restrict__ b_deg0,
    const float* __restrict__ b_deg1,
    const float* __restrict__ b_lin,
    const float* __restrict__ bond_emb,
    const int* __restrict__ n2p_col,
    const int* __restrict__ pool_row,
    const __bf16* __restrict__ ws_bf,
    float* __restrict__ out) {
  // R9: 512-thread / 8-wave blocks, ONE 16-p tile per wave (block still covers
  // 128 p's, grid unchanged). Wave-slot math: 256-thread blocks capped
  // occupancy at 4blk x 4w = 16 waves/CU (50%); 512-thread blocks allow
  // 4blk x 8w = 32 waves/CU (100%). More waves = more outstanding random
  // gathers absorbing the L2/L3 service-rate queue (the measured bottleneck;
  // per-wave latency-hiding attempts R3/R4/R7 all failed). LDS/block
  // unchanged (22.5KB), staging traffic unchanged (8 waves x 1KB/round).
  __shared__ __align__(16) char shbig[18432];
  char (* const fraglds)[8192] = (char(*)[8192])shbig;   // [2][8192]
  __bf16 (* const hs)[16][72] = (__bf16(*)[16][72])shbig; // [8][16][72] epilogue
  __shared__ __align__(16) __bf16 sbond[4][72];
  __shared__ __align__(16) float swdeg0[128][4];
  __shared__ float sbd0[128];
  __shared__ float sbias[64];
  __shared__ float sblin[64];
  __shared__ float sbd1[64];

  const int t = threadIdx.x;
  const int w = t >> 6;      // wave 0..7
  const int l = t & 63;
  const int m = l & 15;
  const int q = l >> 4;
  // block covers 128 p's: wave w owns [bid*128 + w*16, +16)
  const int pbase = blockIdx.x * 128 + w * 16;
  const bool valid = pbase < P_PERM;
  const int pbc = valid ? pbase : (P_PERM - 16);

  // ---- stage small LDS tables ----
  if (t < 256) sbond[t >> 6][t & 63] = (__bf16)bond_emb[t];
  if (t < 128) {
    *(float4*)&swdeg0[t][0] = *(const float4*)(w_deg0 + t * 4);
    sbd0[t] = b_deg0[t];
  } else if (t < 192) {
    int c = t - 128;
    sbias[c] = bias[c]; sblin[c] = b_lin[c]; sbd1[c] = b_deg1[c];
  }

  const unsigned char* __restrict__ nf8 = (const unsigned char*)ws_bf + NF8_OFF;
  const bf16x8* __restrict__ WLv  = (const bf16x8*)(ws_bf + WLF_OFF / 2);
  const bf16x8* __restrict__ WD1v = (const bf16x8*)(ws_bf + WD1F_OFF / 2);
  const unsigned* __restrict__ bep = (const unsigned*)((const char*)ws_bf + BE_OFF);
  const char* __restrict__ W2bytes = (const char*)ws_bf + W2F_OFF;

  // ---- wave-cooperative idx preload: 1 KB per array covers all 16 rounds ----
  intx4 nvx, evx, ncx;
  int bex;
  {
    size_t rb = (size_t)pbc * 16;
    nvx = *(const intx4*)(n2p_val + rb + 4 * l);
    evx = *(const intx4*)(e2p_val + rb + 4 * l);
    ncx = *(const intx4*)(n2p_col + rb + 4 * l);
    bex = (int)bep[(size_t)pbc * 4 + l];
  }
  const int selbase = m * 16;  // byte selector base: src_lane = m*4 + (a>>2)

  // W2 chunk staging: wave w stages its 1KB eighth of the 8 KB chunk
  auto stage = [&](int a, int buf) {
    const char* g = W2bytes + (size_t)a * 8192 + w * 1024 + l * 16;
    char* lds = &fraglds[buf][w * 1024];
    __builtin_amdgcn_global_load_lds(
        (const __attribute__((address_space(1))) unsigned*)g,
        (__attribute__((address_space(3))) unsigned*)lds, 16, 0, 0);
  };
  // gather one node row slice: 2 x 8B of fp8 (row = 64B = ONE cache line)
  auto gath = [&](int nc, uintx2* g) {
    #pragma unroll
    for (int ks = 0; ks < 2; ++ks) {
      if (BF16FEAT) {
        g[ks] = *(const uintx2*)(nf8 + (size_t)nc * 64 + ks * 32 + q * 8);
      } else {
        int k0 = ks * 32 + q * 8;
        float4 n0 = *(const float4*)(nfeat + (size_t)nc * 64 + k0);
        float4 n1 = *(const float4*)(nfeat + (size_t)nc * 64 + k0 + 4);
        uintx2 o;
        o.x = pack_fp8x4(n0.x, n0.y, n0.z, n0.w);
        o.y = pack_fp8x4(n1.x, n1.y, n1.z, n1.w);
        g[ks] = o;
      }
    }
  };

  floatx4 acc[4] = {};
  float dsnv[4];
  int dsnc[4];
  float nv0, ev0;
  int nc0, be0;
  uintx2 g_cur[2], g_nxt[2];

  // prologue: round-0 idx via bpermute, gathers, stage chunk 0
  nv0 = __int_as_float(__builtin_amdgcn_ds_bpermute(selbase, nvx[0]));
  ev0 = __int_as_float(__builtin_amdgcn_ds_bpermute(selbase, evx[0]));
  nc0 = __builtin_amdgcn_ds_bpermute(selbase, ncx[0]);
  be0 = (__builtin_amdgcn_ds_bpermute(selbase, bex)) & 0xff;
  gath(nc0, g_cur);
  stage(0, 0);
  __syncthreads();

  #pragma unroll
  for (int a = 0; a < 16; ++a) {
    const int buf = a & 1;
    float nv1, ev1;
    int nc1, be1;
    if (a < 15) {
      const int an = a + 1;
      const int sel1 = selbase + (an >> 2) * 4;
      const int sl = an & 3;
      nv1 = __int_as_float(__builtin_amdgcn_ds_bpermute(sel1, nvx[sl]));
      ev1 = __int_as_float(__builtin_amdgcn_ds_bpermute(sel1, evx[sl]));
      nc1 = __builtin_amdgcn_ds_bpermute(sel1, ncx[sl]);
      be1 = (__builtin_amdgcn_ds_bpermute(sel1, bex) >> (sl * 8)) & 0xff;
      stage(a + 1, buf ^ 1);
      gath(nc1, g_nxt);
    }

    // compute round a
    bf16x8 afv[2];
    #pragma unroll
    for (int ks = 0; ks < 2; ++ks) {
      bf16x8 eb = *(const bf16x8*)&sbond[be0][ks * 32 + q * 8];
      uintx2 gw = g_cur[ks];
      floatx2 x01 = unpk_fp8_lo(gw.x);
      floatx2 x23 = unpk_fp8_hi(gw.x);
      floatx2 x45 = unpk_fp8_lo(gw.y);
      floatx2 x67 = unpk_fp8_hi(gw.y);
      float xs[8] = {x01.x, x01.y, x23.x, x23.y, x45.x, x45.y, x67.x, x67.y};
      bf16x8 af;
      #pragma unroll
      for (int j = 0; j < 8; ++j)
        af[j] = (__bf16)fmaf(nv0, xs[j], ev0 * (float)eb[j]);
      afv[ks] = af;
    }
    #pragma unroll
    for (int ks = 0; ks < 2; ++ks)
      #pragma unroll
      for (int ct = 0; ct < 4; ++ct) {
        bf16x8 frag = *(const bf16x8*)&fraglds[buf][((ks * 4 + ct) * 64 + l) * 16];
        acc[ct] = __builtin_amdgcn_mfma_f32_16x16x32_bf16(afv[ks], frag, acc[ct], 0, 0, 0);
      }

    // deg_sel fold at a = 0,5,10,15: record nv/node; random degs load DEFERRED
    if (a == 0 || a == 5 || a == 10 || a == 15) {
      const int jj = a / 5;
      dsnv[jj] = nv0;
      dsnc[jj] = nc0;
    }

    if (a < 15) {
      __syncthreads();
      nv0 = nv1; ev0 = ev1; nc0 = nc1; be0 = be1;
      g_cur[0] = g_nxt[0]; g_cur[1] = g_nxt[1];
    }
  }

  // deferred deg gathers: 4 independent random loads; first use is the g-MLP,
  // so latency overlaps the hs/acc2 section below.
  float dsreg[4];
  #pragma unroll
  for (int jj = 0; jj < 4; ++jj)
    dsreg[jj] = dsnv[jj] * degs[dsnc[jj]];

  // fraglds reads of round 15 must complete in ALL waves before hs (union'd)
  // is written.
  __syncthreads();

  // ---- hr = relu(acc + bias) -> LDS (A-frag layout) -> @ w_lin^T ----
  floatx4 acc2[4] = {};
  {
    #pragma unroll
    for (int ct = 0; ct < 4; ++ct) {
      float bv = sbias[ct * 16 + m];
      #pragma unroll
      for (int rr = 0; rr < 4; ++rr)
        hs[w][q * 4 + rr][ct * 16 + m] =
            (__bf16)fmaxf(acc[ct][rr] + bv, 0.0f);
    }
    #pragma unroll
    for (int ks = 0; ks < 2; ++ks) {
      bf16x8 af2 = *(const bf16x8*)&hs[w][m][ks * 32 + q * 8];
      #pragma unroll
      for (int ct = 0; ct < 4; ++ct) {
        bf16x8 frag = WLv[(ks * 4 + ct) * 64 + l];
        acc2[ct] = __builtin_amdgcn_mfma_f32_16x16x32_bf16(af2, frag, acc2[ct], 0, 0, 0);
      }
    }
  }

  // ---- g-MLP (w_deg0/b_deg0 from LDS) ----
  floatx4 gacc[4] = {};
  #pragma unroll
  for (int ks = 0; ks < 4; ++ks) {
    const int k0 = ks * 32 + q * 8;
    bf16x8 af;
    #pragma unroll
    for (int j = 0; j < 8; ++j) {
      int k = k0 + j;
      float4 wr = *(const float4*)&swdeg0[k][0];
      float v = sbd0[k];
      v = fmaf(dsreg[0], wr.x, v);
      v = fmaf(dsreg[1], wr.y, v);
      v = fmaf(dsreg[2], wr.z, v);
      v = fmaf(dsreg[3], wr.w, v);
      af[j] = (__bf16)fmaxf(v, 0.0f);
    }
    #pragma unroll
    for (int ct = 0; ct < 4; ++ct) {
      bf16x8 frag = WD1v[(ks * 4 + ct) * 64 + l];
      gacc[ct] = __builtin_amdgcn_mfma_f32_16x16x32_bf16(af, frag, gacc[ct], 0, 0, 0);
    }
  }

  // ---- h2 = (acc2 + b_lin) * (gacc + b_deg1); pooled scatter ----
  if (valid) {
    intx4   pr4 = *(const intx4*)(pool_row + pbase + q * 4);
    floatx4 pv4 = *(const floatx4*)(pool_val + pbase + q * 4);
    #pragma unroll
    for (int rr = 0; rr < 4; ++rr) {
      float* orow = out + (size_t)pr4[rr] * 64;
      float pv = pv4[rr];
      #pragma unroll
      for (int ct = 0; ct < 4; ++ct) {
        float h2 = (acc2[ct][rr] + sblin[ct * 16 + m]) *
                   (gacc[ct][rr] + sbd1[ct * 16 + m]);
        atomicAdd(orow + ct * 16 + m, pv * h2);
      }
    }
  }
}

extern "C" void kernel_launch(void* const* d_in, const int* in_sizes, int n_in,
                              void* d_out, int out_size, void* d_ws, size_t ws_size,
                              hipStream_t stream) {
  const float* nfeat    = (const float*)d_in[0];
  const float* degs     = (const float*)d_in[1];
  const float* n2p_val  = (const float*)d_in[2];
  const float* e2p_val  = (const float*)d_in[3];
  const float* pool_val = (const float*)d_in[4];
  const float* weights  = (const float*)d_in[5];
  const float* bias     = (const float*)d_in[6];
  const float* w_deg0   = (const float*)d_in[7];
  const float* b_deg0   = (const float*)d_in[8];
  const float* w_deg1   = (const float*)d_in[9];
  const float* b_deg1   = (const float*)d_in[10];
  const float* w_lin    = (const float*)d_in[11];
  const float* b_lin    = (const float*)d_in[12];
  const float* bond_emb = (const float*)d_in[13];
  const int* edge_feat_idx = (const int*)d_in[14];
  const int* n2p_col    = (const int*)d_in[16];
  const int* e2p_col    = (const int*)d_in[18];
  const int* pool_row   = (const int*)d_in[19];

  float* out = (float*)d_out;
  __bf16* ws_bf = (__bf16*)d_ws;

  zero_out_kernel<<<6250, 256, 0, stream>>>((float4*)out);
  prep_all_kernel<<<6554, 256, 0, stream>>>(weights, w_lin, w_deg1, nfeat,
                                            e2p_col, edge_feat_idx, ws_bf);

  int grid = (P_PERM + 127) / 128;  // 1563
  if (ws_size >= WS_NEED_FULL) {
    lrp_mfma_kernel<true><<<grid, 512, 0, stream>>>(
        nfeat, degs, n2p_val, e2p_val, pool_val, bias, w_deg0, b_deg0,
        b_deg1, b_lin, bond_emb, n2p_col, pool_row, ws_bf, out);
  } else {
    lrp_mfma_kernel<false><<<grid, 512, 0, stream>>>(
        nfeat, degs, n2p_val, e2p_val, pool_val, bias, w_deg0, b_deg0,
        b_deg1, b_lin, bond_emb, n2p_col, pool_row, ws_bf, out);
  }
}

// Round 10
// 286.559 us; speedup vs baseline: 1.0064x; 1.0064x over previous
//
#include <hip/hip_runtime.h>
#include <hip/hip_bf16.h>

typedef __attribute__((ext_vector_type(8))) __bf16 bf16x8;
typedef __attribute__((ext_vector_type(4))) float floatx4;
typedef __attribute__((ext_vector_type(2))) float floatx2;
typedef __attribute__((ext_vector_type(4))) int intx4;
typedef __attribute__((ext_vector_type(2))) unsigned uintx2;

constexpr int N_NODES = 100000;
constexpr int P_PERM  = 200000;

// ws layout (bytes)
constexpr size_t W2F_OFF  = 0;          // [16][2][4][64][8] bf16 = 131072 B (8192 B per a)
constexpr size_t WLF_OFF  = 131072;     // [2][4][64][8]  bf16 = 8192 B
constexpr size_t WD1F_OFF = 139264;     // [4][4][64][8]  bf16 = 16384 B
constexpr size_t BE_OFF   = 155648;     // [P*16] u8 packed = 3.2e6 B
constexpr size_t NF8_OFF  = 3355648;    // [100000][64] fp8 e4m3 = 6.4e6 B
constexpr size_t WS_NEED_FULL = 3355648 + (size_t)N_NODES * 64;

// HW fp8 e4m3 (OCP on gfx950) pack/unpack
__device__ inline unsigned pack_fp8x4(float x0, float x1, float x2, float x3) {
  int w = __builtin_amdgcn_cvt_pk_fp8_f32(x0, x1, 0, false);
  w = __builtin_amdgcn_cvt_pk_fp8_f32(x2, x3, w, true);
  return (unsigned)w;
}
__device__ inline floatx2 unpk_fp8_lo(unsigned w) {
  return __builtin_amdgcn_cvt_pk_f32_fp8((int)w, false);
}
__device__ inline floatx2 unpk_fp8_hi(unsigned w) {
  return __builtin_amdgcn_cvt_pk_f32_fp8((int)w, true);
}

// ---- out zeroing ----
__global__ void zero_out_kernel(float4* __restrict__ out) {
  out[blockIdx.x * 256 + threadIdx.x] = make_float4(0.f, 0.f, 0.f, 0.f);
}

// ---- lean prep: 6554 blocks ----
__global__ void prep_all_kernel(const float* __restrict__ weights,
                                const float* __restrict__ w_lin,
                                const float* __restrict__ w_deg1,
                                const float* __restrict__ nfeat,
                                const int* __restrict__ e2p_col,
                                const int* __restrict__ edge_feat_idx,
                                __bf16* __restrict__ ws_bf) {
  int b = blockIdx.x;
  int t = threadIdx.x;
  if (b < 304) {
    int i = b * 256 + t;
    if (i < 65536) {
      int j = i & 7, l = (i >> 3) & 63, ct = (i >> 9) & 3, ks = (i >> 11) & 1, a = i >> 12;
      int k = ks * 32 + (l >> 4) * 8 + j;
      int c = ct * 16 + (l & 15);
      ws_bf[W2F_OFF / 2 + i] = (__bf16)weights[k * 1024 + c * 16 + a];
    } else if (i < 65536 + 4096) {
      int i2 = i - 65536;
      int j = i2 & 7, l = (i2 >> 3) & 63, ct = (i2 >> 9) & 3, ks = (i2 >> 11) & 1;
      int k = ks * 32 + (l >> 4) * 8 + j;
      int c = ct * 16 + (l & 15);
      ws_bf[WLF_OFF / 2 + i2] = (__bf16)w_lin[c * 64 + k];
    } else if (i < 65536 + 4096 + 8192) {
      int i3 = i - 65536 - 4096;
      int j = i3 & 7, l = (i3 >> 3) & 63, ct = (i3 >> 9) & 3, ks = (i3 >> 11) & 3;
      int k = ks * 32 + (l >> 4) * 8 + j;
      int c = ct * 16 + (l & 15);
      ws_bf[WD1F_OFF / 2 + i3] = (__bf16)w_deg1[c * 128 + k];
    }
  } else if (b < 3429) {
    int i = (b - 304) * 256 + t;
    if (i < N_NODES * 8) {
      float4 a = *(const float4*)(nfeat + (size_t)i * 8);
      float4 c = *(const float4*)(nfeat + (size_t)i * 8 + 4);
      uintx2 o;
      o.x = pack_fp8x4(a.x, a.y, a.z, a.w);
      o.y = pack_fp8x4(c.x, c.y, c.z, c.w);
      *(uintx2*)((char*)ws_bf + NF8_OFF + (size_t)i * 8) = o;
    }
  } else {
    int i = (b - 3429) * 256 + t;
    if (i < P_PERM * 4) {
      int4 ec = ((const int4*)e2p_col)[i];
      unsigned v = (unsigned)(edge_feat_idx[ec.x] & 0xff)
                 | ((unsigned)(edge_feat_idx[ec.y] & 0xff) << 8)
                 | ((unsigned)(edge_feat_idx[ec.z] & 0xff) << 16)
                 | ((unsigned)(edge_feat_idx[ec.w] & 0xff) << 24);
      ((unsigned*)((char*)ws_bf + BE_OFF))[i] = v;
    }
  }
}

template <bool BF16FEAT>
__global__ __launch_bounds__(256, 4) void lrp_mfma_kernel(
    const float* __restrict__ nfeat,
    const float* __restrict__ degs,
    const float* __restrict__ n2p_val,
    const float* __restrict__ e2p_val,
    const float* __restrict__ pool_val,
    const float* __restrict__ bias,
    const float* __restrict__ w_deg0,
    const float* __restrict__ b_deg0,
    const float* __restrict__ b_deg1,
    const float* __restrict__ b_lin,
    const float* __restrict__ bond_emb,
    const int* __restrict__ n2p_col,
    const int* __restrict__ pool_row,
    const __bf16* __restrict__ ws_bf,
    float* __restrict__ out) {
  // R10: amortized staging. The per-round __syncthreads (vmcnt(0) drain of the
  // prefetched gathers, 15x per block, lockstep) is the measured stall; R3/R7
  // showed W2 must stay in LDS and counted-vmcnt can't be made correct. So:
  // stage FOUR rounds' W2 chunks (32KB) per period -> barriers 15 -> 6, and
  // 12 of 16 rounds run barrier-free (intra-wave gather prefetch pipelining
  // survives). Compute structure = R6/R8 verified code (2 tiles/wave, fp8
  // gathers, deferred degs). LDS 36.7KB -> 4 blocks/CU (same 16-wave cap).
  __shared__ __align__(16) char shbig[32768];   // [4][8192] W2 period buffer
  __bf16 (* const hs)[2][16][72] = (__bf16(*)[2][16][72])shbig; // epilogue union
  __shared__ __align__(16) __bf16 sbond[4][72];
  __shared__ __align__(16) float swdeg0[128][4];
  __shared__ float sbd0[128];
  __shared__ float sbias[64];
  __shared__ float sblin[64];
  __shared__ float sbd1[64];

  const int t = threadIdx.x;
  const int w = t >> 6;
  const int l = t & 63;
  const int m = l & 15;
  const int q = l >> 4;
  // block covers 128 p's: wave w gets [bid*128 + w*32, +32)
  const int pbase = blockIdx.x * 128 + w * 32;
  int pb[2]  = {pbase, pbase + 16};
  bool valid[2];
  int pbc[2];
  #pragma unroll
  for (int pt = 0; pt < 2; ++pt) {
    valid[pt] = pb[pt] < P_PERM;
    pbc[pt] = valid[pt] ? pb[pt] : (P_PERM - 16);
  }

  // ---- stage small LDS tables ----
  if (t < 256) sbond[t >> 6][t & 63] = (__bf16)bond_emb[t];
  if (t < 128) {
    *(float4*)&swdeg0[t][0] = *(const float4*)(w_deg0 + t * 4);
    sbd0[t] = b_deg0[t];
  } else if (t < 192) {
    int c = t - 128;
    sbias[c] = bias[c]; sblin[c] = b_lin[c]; sbd1[c] = b_deg1[c];
  }

  const unsigned char* __restrict__ nf8 = (const unsigned char*)ws_bf + NF8_OFF;
  const bf16x8* __restrict__ WLv  = (const bf16x8*)(ws_bf + WLF_OFF / 2);
  const bf16x8* __restrict__ WD1v = (const bf16x8*)(ws_bf + WD1F_OFF / 2);
  const unsigned* __restrict__ bep = (const unsigned*)((const char*)ws_bf + BE_OFF);
  const char* __restrict__ W2bytes = (const char*)ws_bf + W2F_OFF;

  // ---- wave-cooperative idx preloads: 1 KB per (array, pt) covers all 16 rounds ----
  intx4 nvx[2], evx[2], ncx[2];
  int bex[2];
  #pragma unroll
  for (int pt = 0; pt < 2; ++pt) {
    size_t rb = (size_t)pbc[pt] * 16;
    nvx[pt] = *(const intx4*)(n2p_val + rb + 4 * l);
    evx[pt] = *(const intx4*)(e2p_val + rb + 4 * l);
    ncx[pt] = *(const intx4*)(n2p_col + rb + 4 * l);
    bex[pt] = (int)bep[(size_t)pbc[pt] * 4 + l];
  }
  const int selbase = m * 16;  // byte selector base: src_lane = m*4 + (a>>2)

  // period staging: 4 chunks (32KB); wave w stages its quarter of each chunk
  auto stage4 = [&](int period) {
    #pragma unroll
    for (int c = 0; c < 4; ++c) {
      #pragma unroll
      for (int j = 0; j < 2; ++j) {
        const char* g = W2bytes + (size_t)(period * 4 + c) * 8192 +
                        (w * 2 + j) * 1024 + l * 16;
        char* lds = &shbig[c * 8192 + (w * 2 + j) * 1024];
        __builtin_amdgcn_global_load_lds(
            (const __attribute__((address_space(1))) unsigned*)g,
            (__attribute__((address_space(3))) unsigned*)lds, 16, 0, 0);
      }
    }
  };
  // gather one node row slice: 2 x 8B of fp8 (row = 64B = ONE cache line)
  auto gath = [&](int nc, uintx2* g) {
    #pragma unroll
    for (int ks = 0; ks < 2; ++ks) {
      if (BF16FEAT) {
        g[ks] = *(const uintx2*)(nf8 + (size_t)nc * 64 + ks * 32 + q * 8);
      } else {
        int k0 = ks * 32 + q * 8;
        float4 n0 = *(const float4*)(nfeat + (size_t)nc * 64 + k0);
        float4 n1 = *(const float4*)(nfeat + (size_t)nc * 64 + k0 + 4);
        uintx2 o;
        o.x = pack_fp8x4(n0.x, n0.y, n0.z, n0.w);
        o.y = pack_fp8x4(n1.x, n1.y, n1.z, n1.w);
        g[ks] = o;
      }
    }
  };

  floatx4 acc[2][4] = {};
  float dsnv[2][4];
  int dsnc[2][4];
  float nv0[2], ev0[2];
  int nc0[2], be0[2];
  uintx2 g_cur[2][2], g_nxt[2][2];

  // prologue: round-0 idx via bpermute, gathers, stage period 0
  #pragma unroll
  for (int pt = 0; pt < 2; ++pt) {
    nv0[pt] = __int_as_float(__builtin_amdgcn_ds_bpermute(selbase, nvx[pt][0]));
    ev0[pt] = __int_as_float(__builtin_amdgcn_ds_bpermute(selbase, evx[pt][0]));
    nc0[pt] = __builtin_amdgcn_ds_bpermute(selbase, ncx[pt][0]);
    be0[pt] = (__builtin_amdgcn_ds_bpermute(selbase, bex[pt])) & 0xff;
    gath(nc0[pt], g_cur[pt]);
  }
  stage4(0);
  __syncthreads();

  #pragma unroll
  for (int a = 0; a < 16; ++a) {
    const int sub = a & 3;   // chunk slot within the period buffer
    float nv1[2], ev1[2];
    int nc1[2], be1[2];
    if (a < 15) {
      const int an = a + 1;
      const int sel1 = selbase + (an >> 2) * 4;
      const int sl = an & 3;
      #pragma unroll
      for (int pt = 0; pt < 2; ++pt) {
        nv1[pt] = __int_as_float(__builtin_amdgcn_ds_bpermute(sel1, nvx[pt][sl]));
        ev1[pt] = __int_as_float(__builtin_amdgcn_ds_bpermute(sel1, evx[pt][sl]));
        nc1[pt] = __builtin_amdgcn_ds_bpermute(sel1, ncx[pt][sl]);
        be1[pt] = (__builtin_amdgcn_ds_bpermute(sel1, bex[pt]) >> (sl * 8)) & 0xff;
      }
      #pragma unroll
      for (int pt = 0; pt < 2; ++pt) gath(nc1[pt], g_nxt[pt]);
    }

    // compute round a (reads shbig[sub])
    bf16x8 afv[2][2];
    #pragma unroll
    for (int pt = 0; pt < 2; ++pt) {
      #pragma unroll
      for (int ks = 0; ks < 2; ++ks) {
        bf16x8 eb = *(const bf16x8*)&sbond[be0[pt]][ks * 32 + q * 8];
        uintx2 gw = g_cur[pt][ks];
        floatx2 x01 = unpk_fp8_lo(gw.x);
        floatx2 x23 = unpk_fp8_hi(gw.x);
        floatx2 x45 = unpk_fp8_lo(gw.y);
        floatx2 x67 = unpk_fp8_hi(gw.y);
        float xs[8] = {x01.x, x01.y, x23.x, x23.y, x45.x, x45.y, x67.x, x67.y};
        bf16x8 af;
        #pragma unroll
        for (int j = 0; j < 8; ++j)
          af[j] = (__bf16)fmaf(nv0[pt], xs[j], ev0[pt] * (float)eb[j]);
        afv[pt][ks] = af;
      }
    }
    #pragma unroll
    for (int ks = 0; ks < 2; ++ks)
      #pragma unroll
      for (int ct = 0; ct < 4; ++ct) {
        bf16x8 frag = *(const bf16x8*)&shbig[sub * 8192 + ((ks * 4 + ct) * 64 + l) * 16];
        acc[0][ct] = __builtin_amdgcn_mfma_f32_16x16x32_bf16(afv[0][ks], frag, acc[0][ct], 0, 0, 0);
        acc[1][ct] = __builtin_amdgcn_mfma_f32_16x16x32_bf16(afv[1][ks], frag, acc[1][ct], 0, 0, 0);
      }

    // deg_sel fold at a = 0,5,10,15: record nv/node; random degs load DEFERRED
    if (a == 0 || a == 5 || a == 10 || a == 15) {
      const int jj = a / 5;
      #pragma unroll
      for (int pt = 0; pt < 2; ++pt) {
        dsnv[pt][jj] = nv0[pt];
        dsnc[pt][jj] = nc0[pt];
      }
    }

    // period boundary: refill the 32KB buffer (only 3x per block)
    if (a < 15 && sub == 3) {
      __syncthreads();           // all waves done reading this period's chunks
      stage4((a + 1) >> 2);
      __syncthreads();           // staging landed (vmcnt(0) implied)
    }

    if (a < 15) {
      #pragma unroll
      for (int pt = 0; pt < 2; ++pt) {
        nv0[pt] = nv1[pt]; ev0[pt] = ev1[pt]; nc0[pt] = nc1[pt]; be0[pt] = be1[pt];
        g_cur[pt][0] = g_nxt[pt][0]; g_cur[pt][1] = g_nxt[pt][1];
      }
    }
  }

  // deferred deg gathers: 8 independent random loads; first use is the g-MLP,
  // so latency overlaps the hs/acc2 section below.
  float dsreg[2][4];
  #pragma unroll
  for (int pt = 0; pt < 2; ++pt)
    #pragma unroll
    for (int jj = 0; jj < 4; ++jj)
      dsreg[pt][jj] = dsnv[pt][jj] * degs[dsnc[pt][jj]];

  // W2 reads of round 15 must complete in ALL waves before hs (union'd in
  // shbig) is written.
  __syncthreads();

  // ---- hr = relu(acc + bias) -> LDS (A-frag layout) -> @ w_lin^T ----
  floatx4 acc2[2][4] = {};
  {
    #pragma unroll
    for (int pt = 0; pt < 2; ++pt)
      #pragma unroll
      for (int ct = 0; ct < 4; ++ct) {
        float bv = sbias[ct * 16 + m];
        #pragma unroll
        for (int rr = 0; rr < 4; ++rr)
          hs[w][pt][q * 4 + rr][ct * 16 + m] =
              (__bf16)fmaxf(acc[pt][ct][rr] + bv, 0.0f);
      }
    #pragma unroll
    for (int pt = 0; pt < 2; ++pt)
      #pragma unroll
      for (int ks = 0; ks < 2; ++ks) {
        bf16x8 af2 = *(const bf16x8*)&hs[w][pt][m][ks * 32 + q * 8];
        #pragma unroll
        for (int ct = 0; ct < 4; ++ct) {
          bf16x8 frag = WLv[(ks * 4 + ct) * 64 + l];
          acc2[pt][ct] = __builtin_amdgcn_mfma_f32_16x16x32_bf16(af2, frag, acc2[pt][ct], 0, 0, 0);
        }
      }
  }

  // ---- g-MLP (w_deg0/b_deg0 from LDS) ----
  floatx4 gacc[2][4] = {};
  #pragma unroll
  for (int ks = 0; ks < 4; ++ks) {
    const int k0 = ks * 32 + q * 8;
    bf16x8 af[2];
    #pragma unroll
    for (int j = 0; j < 8; ++j) {
      int k = k0 + j;
      float4 wr = *(const float4*)&swdeg0[k][0];
      float bk = sbd0[k];
      #pragma unroll
      for (int pt = 0; pt < 2; ++pt) {
        float v = bk;
        v = fmaf(dsreg[pt][0], wr.x, v);
        v = fmaf(dsreg[pt][1], wr.y, v);
        v = fmaf(dsreg[pt][2], wr.z, v);
        v = fmaf(dsreg[pt][3], wr.w, v);
        af[pt][j] = (__bf16)fmaxf(v, 0.0f);
      }
    }
    #pragma unroll
    for (int ct = 0; ct < 4; ++ct) {
      bf16x8 frag = WD1v[(ks * 4 + ct) * 64 + l];
      gacc[0][ct] = __builtin_amdgcn_mfma_f32_16x16x32_bf16(af[0], frag, gacc[0][ct], 0, 0, 0);
      gacc[1][ct] = __builtin_amdgcn_mfma_f32_16x16x32_bf16(af[1], frag, gacc[1][ct], 0, 0, 0);
    }
  }

  // ---- h2 = (acc2 + b_lin) * (gacc + b_deg1); pooled scatter ----
  #pragma unroll
  for (int pt = 0; pt < 2; ++pt) {
    if (!valid[pt]) continue;
    intx4   pr4 = *(const intx4*)(pool_row + pb[pt] + q * 4);
    floatx4 pv4 = *(const floatx4*)(pool_val + pb[pt] + q * 4);
    #pragma unroll
    for (int rr = 0; rr < 4; ++rr) {
      float* orow = out + (size_t)pr4[rr] * 64;
      float pv = pv4[rr];
      #pragma unroll
      for (int ct = 0; ct < 4; ++ct) {
        float h2 = (acc2[pt][ct][rr] + sblin[ct * 16 + m]) *
                   (gacc[pt][ct][rr] + sbd1[ct * 16 + m]);
        atomicAdd(orow + ct * 16 + m, pv * h2);
      }
    }
  }
}

extern "C" void kernel_launch(void* const* d_in, const int* in_sizes, int n_in,
                              void* d_out, int out_size, void* d_ws, size_t ws_size,
                              hipStream_t stream) {
  const float* nfeat    = (const float*)d_in[0];
  const float* degs     = (const float*)d_in[1];
  const float* n2p_val  = (const float*)d_in[2];
  const float* e2p_val  = (const float*)d_in[3];
  const float* pool_val = (const float*)d_in[4];
  const float* weights  = (const float*)d_in[5];
  const float* bias     = (const float*)d_in[6];
  const float* w_deg0   = (const float*)d_in[7];
  const float* b_deg0   = (const float*)d_in[8];
  const float* w_deg1   = (const float*)d_in[9];
  const float* b_deg1   = (const float*)d_in[10];
  const float* w_lin    = (const float*)d_in[11];
  const float* b_lin    = (const float*)d_in[12];
  const float* bond_emb = (const float*)d_in[13];
  const int* edge_feat_idx = (const int*)d_in[14];
  const int* n2p_col    = (const int*)d_in[16];
  const int* e2p_col    = (const int*)d_in[18];
  const int* pool_row   = (const int*)d_in[19];

  float* out = (float*)d_out;
  __bf16* ws_bf = (__bf16*)d_ws;

  zero_out_kernel<<<6250, 256, 0, stream>>>((float4*)out);
  prep_all_kernel<<<6554, 256, 0, stream>>>(weights, w_lin, w_deg1, nfeat,
                                            e2p_col, edge_feat_idx, ws_bf);

  int grid = (P_PERM + 127) / 128;  // 1563
  if (ws_size >= WS_NEED_FULL) {
    lrp_mfma_kernel<true><<<grid, 256, 0, stream>>>(
        nfeat, degs, n2p_val, e2p_val, pool_val, bias, w_deg0, b_deg0,
        b_deg1, b_lin, bond_emb, n2p_col, pool_row, ws_bf, out);
  } else {
    lrp_mfma_kernel<false><<<grid, 256, 0, stream>>>(
        nfeat, degs, n2p_val, e2p_val, pool_val, bias, w_deg0, b_deg0,
        b_deg1, b_lin, bond_emb, n2p_col, pool_row, ws_bf, out);
  }
}

// Round 11
// 276.786 us; speedup vs baseline: 1.0419x; 1.0353x over previous
//
#include <hip/hip_runtime.h>
#include <hip/hip_bf16.h>

typedef __attribute__((ext_vector_type(8))) __bf16 bf16x8;
typedef __attribute__((ext_vector_type(4))) float floatx4;
typedef __attribute__((ext_vector_type(2))) float floatx2;
typedef __attribute__((ext_vector_type(4))) int intx4;
typedef __attribute__((ext_vector_type(2))) unsigned uintx2;

constexpr int N_NODES = 100000;
constexpr int P_PERM  = 200000;

// ws layout (bytes)
constexpr size_t W2F_OFF  = 0;          // [16][2][4][64][8] bf16 = 131072 B (8192 B per a)
constexpr size_t WLF_OFF  = 131072;     // [2][4][64][8]  bf16 = 8192 B
constexpr size_t WD1F_OFF = 139264;     // [4][4][64][8]  bf16 = 16384 B
constexpr size_t BE_OFF   = 155648;     // [P*16] u8 packed = 3.2e6 B
constexpr size_t NF8_OFF  = 3355648;    // [100000][64] fp8 e4m3 = 6.4e6 B
constexpr size_t WS_NEED_FULL = 3355648 + (size_t)N_NODES * 64;

// HW fp8 e4m3 (OCP on gfx950) pack/unpack
__device__ inline unsigned pack_fp8x4(float x0, float x1, float x2, float x3) {
  int w = __builtin_amdgcn_cvt_pk_fp8_f32(x0, x1, 0, false);
  w = __builtin_amdgcn_cvt_pk_fp8_f32(x2, x3, w, true);
  return (unsigned)w;
}
__device__ inline floatx2 unpk_fp8_lo(unsigned w) {
  return __builtin_amdgcn_cvt_pk_f32_fp8((int)w, false);
}
__device__ inline floatx2 unpk_fp8_hi(unsigned w) {
  return __builtin_amdgcn_cvt_pk_f32_fp8((int)w, true);
}

// ---- fused prep (R6-style merged: zeroing + tables in ONE launch; the
// zeroing blocks run concurrently with the table/pack blocks) ----
__global__ void prep_all_kernel(float4* __restrict__ out,
                                const float* __restrict__ weights,
                                const float* __restrict__ w_lin,
                                const float* __restrict__ w_deg1,
                                const float* __restrict__ nfeat,
                                const int* __restrict__ e2p_col,
                                const int* __restrict__ edge_feat_idx,
                                __bf16* __restrict__ ws_bf) {
  int b = blockIdx.x;
  int t = threadIdx.x;
  if (b < 6250) {
    out[b * 256 + t] = make_float4(0.f, 0.f, 0.f, 0.f);
  } else if (b < 6554) {
    int i = (b - 6250) * 256 + t;
    if (i < 65536) {
      int j = i & 7, l = (i >> 3) & 63, ct = (i >> 9) & 3, ks = (i >> 11) & 1, a = i >> 12;
      int k = ks * 32 + (l >> 4) * 8 + j;
      int c = ct * 16 + (l & 15);
      ws_bf[W2F_OFF / 2 + i] = (__bf16)weights[k * 1024 + c * 16 + a];
    } else if (i < 65536 + 4096) {
      int i2 = i - 65536;
      int j = i2 & 7, l = (i2 >> 3) & 63, ct = (i2 >> 9) & 3, ks = (i2 >> 11) & 1;
      int k = ks * 32 + (l >> 4) * 8 + j;
      int c = ct * 16 + (l & 15);
      ws_bf[WLF_OFF / 2 + i2] = (__bf16)w_lin[c * 64 + k];
    } else if (i < 65536 + 4096 + 8192) {
      int i3 = i - 65536 - 4096;
      int j = i3 & 7, l = (i3 >> 3) & 63, ct = (i3 >> 9) & 3, ks = (i3 >> 11) & 3;
      int k = ks * 32 + (l >> 4) * 8 + j;
      int c = ct * 16 + (l & 15);
      ws_bf[WD1F_OFF / 2 + i3] = (__bf16)w_deg1[c * 128 + k];
    }
  } else if (b < 9679) {
    int i = (b - 6554) * 256 + t;
    if (i < N_NODES * 8) {
      float4 a = *(const float4*)(nfeat + (size_t)i * 8);
      float4 c = *(const float4*)(nfeat + (size_t)i * 8 + 4);
      uintx2 o;
      o.x = pack_fp8x4(a.x, a.y, a.z, a.w);
      o.y = pack_fp8x4(c.x, c.y, c.z, c.w);
      *(uintx2*)((char*)ws_bf + NF8_OFF + (size_t)i * 8) = o;
    }
  } else {
    int i = (b - 9679) * 256 + t;
    if (i < P_PERM * 4) {
      int4 ec = ((const int4*)e2p_col)[i];
      unsigned v = (unsigned)(edge_feat_idx[ec.x] & 0xff)
                 | ((unsigned)(edge_feat_idx[ec.y] & 0xff) << 8)
                 | ((unsigned)(edge_feat_idx[ec.z] & 0xff) << 16)
                 | ((unsigned)(edge_feat_idx[ec.w] & 0xff) << 24);
      ((unsigned*)((char*)ws_bf + BE_OFF))[i] = v;
    }
  }
}

template <bool BF16FEAT>
__global__ __launch_bounds__(256, 4) void lrp_mfma_kernel(
    const float* __restrict__ nfeat,
    const float* __restrict__ degs,
    const float* __restrict__ n2p_val,
    const float* __restrict__ e2p_val,
    const float* __restrict__ pool_val,
    const float* __restrict__ bias,
    const float* __restrict__ w_deg0,
    const float* __restrict__ b_deg0,
    const float* __restrict__ b_deg1,
    const float* __restrict__ b_lin,
    const float* __restrict__ bond_emb,
    const int* __restrict__ n2p_col,
    const int* __restrict__ pool_row,
    const __bf16* __restrict__ ws_bf,
    float* __restrict__ out) {
  // R11 = R10 (amortized 4-round staging, barriers 15->6) + DEPTH-2 gather
  // prefetch: gathers for round a+2 issued in round a (3-slot register
  // rotation, statically indexed under full unroll). Register gathers are
  // wave-private, so boundary barriers can't corrupt them (unlike R4/R7's
  // LDS-coupled counted-vmcnt attempts). This doubles per-wave latency
  // hiding in the 12 barrier-free rounds.
  __shared__ __align__(16) char shbig[32768];   // [4][8192] W2 period buffer
  __bf16 (* const hs)[2][16][72] = (__bf16(*)[2][16][72])shbig; // epilogue union
  __shared__ __align__(16) __bf16 sbond[4][72];
  __shared__ __align__(16) float swdeg0[128][4];
  __shared__ float sbd0[128];
  __shared__ float sbias[64];
  __shared__ float sblin[64];
  __shared__ float sbd1[64];

  const int t = threadIdx.x;
  const int w = t >> 6;
  const int l = t & 63;
  const int m = l & 15;
  const int q = l >> 4;
  // block covers 128 p's: wave w gets [bid*128 + w*32, +32)
  const int pbase = blockIdx.x * 128 + w * 32;
  int pb[2]  = {pbase, pbase + 16};
  bool valid[2];
  int pbc[2];
  #pragma unroll
  for (int pt = 0; pt < 2; ++pt) {
    valid[pt] = pb[pt] < P_PERM;
    pbc[pt] = valid[pt] ? pb[pt] : (P_PERM - 16);
  }

  // ---- stage small LDS tables ----
  if (t < 256) sbond[t >> 6][t & 63] = (__bf16)bond_emb[t];
  if (t < 128) {
    *(float4*)&swdeg0[t][0] = *(const float4*)(w_deg0 + t * 4);
    sbd0[t] = b_deg0[t];
  } else if (t < 192) {
    int c = t - 128;
    sbias[c] = bias[c]; sblin[c] = b_lin[c]; sbd1[c] = b_deg1[c];
  }

  const unsigned char* __restrict__ nf8 = (const unsigned char*)ws_bf + NF8_OFF;
  const bf16x8* __restrict__ WLv  = (const bf16x8*)(ws_bf + WLF_OFF / 2);
  const bf16x8* __restrict__ WD1v = (const bf16x8*)(ws_bf + WD1F_OFF / 2);
  const unsigned* __restrict__ bep = (const unsigned*)((const char*)ws_bf + BE_OFF);
  const char* __restrict__ W2bytes = (const char*)ws_bf + W2F_OFF;

  // ---- wave-cooperative idx preloads: 1 KB per (array, pt) covers all 16 rounds ----
  intx4 nvx[2], evx[2], ncx[2];
  int bex[2];
  #pragma unroll
  for (int pt = 0; pt < 2; ++pt) {
    size_t rb = (size_t)pbc[pt] * 16;
    nvx[pt] = *(const intx4*)(n2p_val + rb + 4 * l);
    evx[pt] = *(const intx4*)(e2p_val + rb + 4 * l);
    ncx[pt] = *(const intx4*)(n2p_col + rb + 4 * l);
    bex[pt] = (int)bep[(size_t)pbc[pt] * 4 + l];
  }
  const int selbase = m * 16;  // byte selector base: src_lane = m*4 + (a>>2)

  // period staging: 4 chunks (32KB); wave w stages its quarter of each chunk
  auto stage4 = [&](int period) {
    #pragma unroll
    for (int c = 0; c < 4; ++c) {
      #pragma unroll
      for (int j = 0; j < 2; ++j) {
        const char* g = W2bytes + (size_t)(period * 4 + c) * 8192 +
                        (w * 2 + j) * 1024 + l * 16;
        char* lds = &shbig[c * 8192 + (w * 2 + j) * 1024];
        __builtin_amdgcn_global_load_lds(
            (const __attribute__((address_space(1))) unsigned*)g,
            (__attribute__((address_space(3))) unsigned*)lds, 16, 0, 0);
      }
    }
  };
  // gather one node row slice: 2 x 8B of fp8 (row = 64B = ONE cache line)
  auto gath = [&](int nc, uintx2* g) {
    #pragma unroll
    for (int ks = 0; ks < 2; ++ks) {
      if (BF16FEAT) {
        g[ks] = *(const uintx2*)(nf8 + (size_t)nc * 64 + ks * 32 + q * 8);
      } else {
        int k0 = ks * 32 + q * 8;
        float4 n0 = *(const float4*)(nfeat + (size_t)nc * 64 + k0);
        float4 n1 = *(const float4*)(nfeat + (size_t)nc * 64 + k0 + 4);
        uintx2 o;
        o.x = pack_fp8x4(n0.x, n0.y, n0.z, n0.w);
        o.y = pack_fp8x4(n1.x, n1.y, n1.z, n1.w);
        g[ks] = o;
      }
    }
  };

  floatx4 acc[2][4] = {};
  float dsnv[2][4];
  int dsnc[2][4];
  // idx pipeline: cur (round a), nxt (a+1); a+2 computed in-round
  float nv0[2], ev0[2], nv1[2], ev1[2];
  int nc0[2], be0[2], nc1[2], be1[2];
  uintx2 g[3][2][2];  // 3-slot rotation: round a reads g[a%3], writes g[(a+2)%3]

  // prologue: idx+gathers for rounds 0 and 1; stage period 0
  #pragma unroll
  for (int pt = 0; pt < 2; ++pt) {
    nv0[pt] = __int_as_float(__builtin_amdgcn_ds_bpermute(selbase, nvx[pt][0]));
    ev0[pt] = __int_as_float(__builtin_amdgcn_ds_bpermute(selbase, evx[pt][0]));
    nc0[pt] = __builtin_amdgcn_ds_bpermute(selbase, ncx[pt][0]);
    be0[pt] = (__builtin_amdgcn_ds_bpermute(selbase, bex[pt])) & 0xff;
    gath(nc0[pt], g[0][pt]);
    // round 1: sel = selbase + (1>>2)*4 = selbase, slot 1
    nv1[pt] = __int_as_float(__builtin_amdgcn_ds_bpermute(selbase, nvx[pt][1]));
    ev1[pt] = __int_as_float(__builtin_amdgcn_ds_bpermute(selbase, evx[pt][1]));
    nc1[pt] = __builtin_amdgcn_ds_bpermute(selbase, ncx[pt][1]);
    be1[pt] = (__builtin_amdgcn_ds_bpermute(selbase, bex[pt]) >> 8) & 0xff;
    gath(nc1[pt], g[1][pt]);
  }
  stage4(0);
  __syncthreads();

  #pragma unroll
  for (int a = 0; a < 16; ++a) {
    const int sub = a & 3;       // chunk slot within the period buffer
    const int gcur = a % 3;
    const int gwr  = (a + 2) % 3;
    float nv2[2], ev2[2];
    int nc2[2], be2[2];
    if (a < 14) {
      const int an2 = a + 2;
      const int sel2 = selbase + (an2 >> 2) * 4;
      const int sl2 = an2 & 3;
      #pragma unroll
      for (int pt = 0; pt < 2; ++pt) {
        nv2[pt] = __int_as_float(__builtin_amdgcn_ds_bpermute(sel2, nvx[pt][sl2]));
        ev2[pt] = __int_as_float(__builtin_amdgcn_ds_bpermute(sel2, evx[pt][sl2]));
        nc2[pt] = __builtin_amdgcn_ds_bpermute(sel2, ncx[pt][sl2]);
        be2[pt] = (__builtin_amdgcn_ds_bpermute(sel2, bex[pt]) >> (sl2 * 8)) & 0xff;
      }
      #pragma unroll
      for (int pt = 0; pt < 2; ++pt) gath(nc2[pt], g[gwr][pt]);
    }

    // compute round a (reads g[gcur], shbig[sub])
    bf16x8 afv[2][2];
    #pragma unroll
    for (int pt = 0; pt < 2; ++pt) {
      #pragma unroll
      for (int ks = 0; ks < 2; ++ks) {
        bf16x8 eb = *(const bf16x8*)&sbond[be0[pt]][ks * 32 + q * 8];
        uintx2 gw = g[gcur][pt][ks];
        floatx2 x01 = unpk_fp8_lo(gw.x);
        floatx2 x23 = unpk_fp8_hi(gw.x);
        floatx2 x45 = unpk_fp8_lo(gw.y);
        floatx2 x67 = unpk_fp8_hi(gw.y);
        float xs[8] = {x01.x, x01.y, x23.x, x23.y, x45.x, x45.y, x67.x, x67.y};
        bf16x8 af;
        #pragma unroll
        for (int j = 0; j < 8; ++j)
          af[j] = (__bf16)fmaf(nv0[pt], xs[j], ev0[pt] * (float)eb[j]);
        afv[pt][ks] = af;
      }
    }
    #pragma unroll
    for (int ks = 0; ks < 2; ++ks)
      #pragma unroll
      for (int ct = 0; ct < 4; ++ct) {
        bf16x8 frag = *(const bf16x8*)&shbig[sub * 8192 + ((ks * 4 + ct) * 64 + l) * 16];
        acc[0][ct] = __builtin_amdgcn_mfma_f32_16x16x32_bf16(afv[0][ks], frag, acc[0][ct], 0, 0, 0);
        acc[1][ct] = __builtin_amdgcn_mfma_f32_16x16x32_bf16(afv[1][ks], frag, acc[1][ct], 0, 0, 0);
      }

    // deg_sel fold at a = 0,5,10,15: record nv/node; random degs load DEFERRED
    if (a == 0 || a == 5 || a == 10 || a == 15) {
      const int jj = a / 5;
      #pragma unroll
      for (int pt = 0; pt < 2; ++pt) {
        dsnv[pt][jj] = nv0[pt];
        dsnc[pt][jj] = nc0[pt];
      }
    }

    // period boundary: refill the 32KB buffer (only 3x per block). Register
    // gathers (wave-private) are drained here but never corrupted.
    if (a < 15 && sub == 3) {
      __syncthreads();           // all waves done reading this period's chunks
      stage4((a + 1) >> 2);
      __syncthreads();           // staging landed (vmcnt(0) implied)
    }

    if (a < 15) {
      #pragma unroll
      for (int pt = 0; pt < 2; ++pt) {
        nv0[pt] = nv1[pt]; ev0[pt] = ev1[pt]; nc0[pt] = nc1[pt]; be0[pt] = be1[pt];
      }
    }
    if (a < 14) {
      #pragma unroll
      for (int pt = 0; pt < 2; ++pt) {
        nv1[pt] = nv2[pt]; ev1[pt] = ev2[pt]; nc1[pt] = nc2[pt]; be1[pt] = be2[pt];
      }
    }
  }

  // deferred deg gathers: 8 independent random loads; first use is the g-MLP,
  // so latency overlaps the hs/acc2 section below.
  float dsreg[2][4];
  #pragma unroll
  for (int pt = 0; pt < 2; ++pt)
    #pragma unroll
    for (int jj = 0; jj < 4; ++jj)
      dsreg[pt][jj] = dsnv[pt][jj] * degs[dsnc[pt][jj]];

  // W2 reads of round 15 must complete in ALL waves before hs (union'd in
  // shbig) is written.
  __syncthreads();

  // ---- hr = relu(acc + bias) -> LDS (A-frag layout) -> @ w_lin^T ----
  floatx4 acc2[2][4] = {};
  {
    #pragma unroll
    for (int pt = 0; pt < 2; ++pt)
      #pragma unroll
      for (int ct = 0; ct < 4; ++ct) {
        float bv = sbias[ct * 16 + m];
        #pragma unroll
        for (int rr = 0; rr < 4; ++rr)
          hs[w][pt][q * 4 + rr][ct * 16 + m] =
              (__bf16)fmaxf(acc[pt][ct][rr] + bv, 0.0f);
      }
    #pragma unroll
    for (int pt = 0; pt < 2; ++pt)
      #pragma unroll
      for (int ks = 0; ks < 2; ++ks) {
        bf16x8 af2 = *(const bf16x8*)&hs[w][pt][m][ks * 32 + q * 8];
        #pragma unroll
        for (int ct = 0; ct < 4; ++ct) {
          bf16x8 frag = WLv[(ks * 4 + ct) * 64 + l];
          acc2[pt][ct] = __builtin_amdgcn_mfma_f32_16x16x32_bf16(af2, frag, acc2[pt][ct], 0, 0, 0);
        }
      }
  }

  // ---- g-MLP (w_deg0/b_deg0 from LDS) ----
  floatx4 gacc[2][4] = {};
  #pragma unroll
  for (int ks = 0; ks < 4; ++ks) {
    const int k0 = ks * 32 + q * 8;
    bf16x8 af[2];
    #pragma unroll
    for (int j = 0; j < 8; ++j) {
      int k = k0 + j;
      float4 wr = *(const float4*)&swdeg0[k][0];
      float bk = sbd0[k];
      #pragma unroll
      for (int pt = 0; pt < 2; ++pt) {
        float v = bk;
        v = fmaf(dsreg[pt][0], wr.x, v);
        v = fmaf(dsreg[pt][1], wr.y, v);
        v = fmaf(dsreg[pt][2], wr.z, v);
        v = fmaf(dsreg[pt][3], wr.w, v);
        af[pt][j] = (__bf16)fmaxf(v, 0.0f);
      }
    }
    #pragma unroll
    for (int ct = 0; ct < 4; ++ct) {
      bf16x8 frag = WD1v[(ks * 4 + ct) * 64 + l];
      gacc[0][ct] = __builtin_amdgcn_mfma_f32_16x16x32_bf16(af[0], frag, gacc[0][ct], 0, 0, 0);
      gacc[1][ct] = __builtin_amdgcn_mfma_f32_16x16x32_bf16(af[1], frag, gacc[1][ct], 0, 0, 0);
    }
  }

  // ---- h2 = (acc2 + b_lin) * (gacc + b_deg1); pooled scatter ----
  #pragma unroll
  for (int pt = 0; pt < 2; ++pt) {
    if (!valid[pt]) continue;
    intx4   pr4 = *(const intx4*)(pool_row + pb[pt] + q * 4);
    floatx4 pv4 = *(const floatx4*)(pool_val + pb[pt] + q * 4);
    #pragma unroll
    for (int rr = 0; rr < 4; ++rr) {
      float* orow = out + (size_t)pr4[rr] * 64;
      float pv = pv4[rr];
      #pragma unroll
      for (int ct = 0; ct < 4; ++ct) {
        float h2 = (acc2[pt][ct][rr] + sblin[ct * 16 + m]) *
                   (gacc[pt][ct][rr] + sbd1[ct * 16 + m]);
        atomicAdd(orow + ct * 16 + m, pv * h2);
      }
    }
  }
}

extern "C" void kernel_launch(void* const* d_in, const int* in_sizes, int n_in,
                              void* d_out, int out_size, void* d_ws, size_t ws_size,
                              hipStream_t stream) {
  const float* nfeat    = (const float*)d_in[0];
  const float* degs     = (const float*)d_in[1];
  const float* n2p_val  = (const float*)d_in[2];
  const float* e2p_val  = (const float*)d_in[3];
  const float* pool_val = (const float*)d_in[4];
  const float* weights  = (const float*)d_in[5];
  const float* bias     = (const float*)d_in[6];
  const float* w_deg0   = (const float*)d_in[7];
  const float* b_deg0   = (const float*)d_in[8];
  const float* w_deg1   = (const float*)d_in[9];
  const float* b_deg1   = (const float*)d_in[10];
  const float* w_lin    = (const float*)d_in[11];
  const float* b_lin    = (const float*)d_in[12];
  const float* bond_emb = (const float*)d_in[13];
  const int* edge_feat_idx = (const int*)d_in[14];
  const int* n2p_col    = (const int*)d_in[16];
  const int* e2p_col    = (const int*)d_in[18];
  const int* pool_row   = (const int*)d_in[19];

  float* out = (float*)d_out;
  __bf16* ws_bf = (__bf16*)d_ws;

  prep_all_kernel<<<12804, 256, 0, stream>>>((float4*)out, weights, w_lin,
                                             w_deg1, nfeat, e2p_col,
                                             edge_feat_idx, ws_bf);

  int grid = (P_PERM + 127) / 128;  // 1563
  if (ws_size >= WS_NEED_FULL) {
    lrp_mfma_kernel<true><<<grid, 256, 0, stream>>>(
        nfeat, degs, n2p_val, e2p_val, pool_val, bias, w_deg0, b_deg0,
        b_deg1, b_lin, bond_emb, n2p_col, pool_row, ws_bf, out);
  } else {
    lrp_mfma_kernel<false><<<grid, 256, 0, stream>>>(
        nfeat, degs, n2p_val, e2p_val, pool_val, bias, w_deg0, b_deg0,
        b_deg1, b_lin, bond_emb, n2p_col, pool_row, ws_bf, out);
  }
}

// Round 12
// 267.237 us; speedup vs baseline: 1.0791x; 1.0357x over previous
//
#include <hip/hip_runtime.h>
#include <hip/hip_bf16.h>

typedef __attribute__((ext_vector_type(8))) __bf16 bf16x8;
typedef __attribute__((ext_vector_type(4))) float floatx4;
typedef __attribute__((ext_vector_type(2))) float floatx2;
typedef __attribute__((ext_vector_type(4))) int intx4;
typedef __attribute__((ext_vector_type(2))) unsigned uintx2;
typedef __attribute__((ext_vector_type(4))) unsigned uintx4;

constexpr int N_NODES = 100000;
constexpr int P_PERM  = 200000;

// ws layout (bytes)
constexpr size_t W2F_OFF  = 0;          // [16][2][4][64][8] bf16 = 131072 B (8192 B per a)
constexpr size_t WLF_OFF  = 131072;     // [2][4][64][8]  bf16 = 8192 B
constexpr size_t WD1F_OFF = 139264;     // [4][4][64][8]  bf16 = 16384 B
constexpr size_t BE_OFF   = 155648;     // [P*16] u8 packed = 3.2e6 B
constexpr size_t NF8_OFF  = 3355648;    // [100000][64] fp8 e4m3, BLOCK-INTERLEAVED
constexpr size_t WS_NEED_FULL = 3355648 + (size_t)N_NODES * 64;

// HW fp8 e4m3 (OCP on gfx950) pack/unpack
__device__ inline unsigned pack_fp8x4(float x0, float x1, float x2, float x3) {
  int w = __builtin_amdgcn_cvt_pk_fp8_f32(x0, x1, 0, false);
  w = __builtin_amdgcn_cvt_pk_fp8_f32(x2, x3, w, true);
  return (unsigned)w;
}
__device__ inline floatx2 unpk_fp8_lo(unsigned w) {
  return __builtin_amdgcn_cvt_pk_f32_fp8((int)w, false);
}
__device__ inline floatx2 unpk_fp8_hi(unsigned w) {
  return __builtin_amdgcn_cvt_pk_f32_fp8((int)w, true);
}

// ---- fused prep (merged zeroing + tables; nf8 rows stored block-interleaved:
// row block order [0,4,1,5,2,6,3,7] so MFMA lane (q,m)'s two 8B fragments
// {block q, block q+4} are ADJACENT -> gather = ONE dwordx4 per pt) ----
__global__ void prep_all_kernel(float4* __restrict__ out,
                                const float* __restrict__ weights,
                                const float* __restrict__ w_lin,
                                const float* __restrict__ w_deg1,
                                const float* __restrict__ nfeat,
                                const int* __restrict__ e2p_col,
                                const int* __restrict__ edge_feat_idx,
                                __bf16* __restrict__ ws_bf) {
  int b = blockIdx.x;
  int t = threadIdx.x;
  if (b < 6250) {
    out[b * 256 + t] = make_float4(0.f, 0.f, 0.f, 0.f);
  } else if (b < 6554) {
    int i = (b - 6250) * 256 + t;
    if (i < 65536) {
      int j = i & 7, l = (i >> 3) & 63, ct = (i >> 9) & 3, ks = (i >> 11) & 1, a = i >> 12;
      int k = ks * 32 + (l >> 4) * 8 + j;
      int c = ct * 16 + (l & 15);
      ws_bf[W2F_OFF / 2 + i] = (__bf16)weights[k * 1024 + c * 16 + a];
    } else if (i < 65536 + 4096) {
      int i2 = i - 65536;
      int j = i2 & 7, l = (i2 >> 3) & 63, ct = (i2 >> 9) & 3, ks = (i2 >> 11) & 1;
      int k = ks * 32 + (l >> 4) * 8 + j;
      int c = ct * 16 + (l & 15);
      ws_bf[WLF_OFF / 2 + i2] = (__bf16)w_lin[c * 64 + k];
    } else if (i < 65536 + 4096 + 8192) {
      int i3 = i - 65536 - 4096;
      int j = i3 & 7, l = (i3 >> 3) & 63, ct = (i3 >> 9) & 3, ks = (i3 >> 11) & 3;
      int k = ks * 32 + (l >> 4) * 8 + j;
      int c = ct * 16 + (l & 15);
      ws_bf[WD1F_OFF / 2 + i3] = (__bf16)w_deg1[c * 128 + k];
    }
  } else if (b < 9679) {
    int i = (b - 6554) * 256 + t;
    if (i < N_NODES * 8) {
      int node = i >> 3;
      int blk  = i & 7;                       // source 8B block within row
      int dst  = (blk < 4) ? (blk * 2) : ((blk - 4) * 2 + 1);  // interleave
      float4 a = *(const float4*)(nfeat + (size_t)i * 8);
      float4 c = *(const float4*)(nfeat + (size_t)i * 8 + 4);
      uintx2 o;
      o.x = pack_fp8x4(a.x, a.y, a.z, a.w);
      o.y = pack_fp8x4(c.x, c.y, c.z, c.w);
      *(uintx2*)((char*)ws_bf + NF8_OFF + (size_t)node * 64 + dst * 8) = o;
    }
  } else {
    int i = (b - 9679) * 256 + t;
    if (i < P_PERM * 4) {
      int4 ec = ((const int4*)e2p_col)[i];
      unsigned v = (unsigned)(edge_feat_idx[ec.x] & 0xff)
                 | ((unsigned)(edge_feat_idx[ec.y] & 0xff) << 8)
                 | ((unsigned)(edge_feat_idx[ec.z] & 0xff) << 16)
                 | ((unsigned)(edge_feat_idx[ec.w] & 0xff) << 24);
      ((unsigned*)((char*)ws_bf + BE_OFF))[i] = v;
    }
  }
}

template <bool BF16FEAT>
__global__ __launch_bounds__(256, 4) void lrp_mfma_kernel(
    const float* __restrict__ nfeat,
    const float* __restrict__ degs,
    const float* __restrict__ n2p_val,
    const float* __restrict__ e2p_val,
    const float* __restrict__ pool_val,
    const float* __restrict__ bias,
    const float* __restrict__ w_deg0,
    const float* __restrict__ b_deg0,
    const float* __restrict__ b_deg1,
    const float* __restrict__ b_lin,
    const float* __restrict__ bond_emb,
    const int* __restrict__ n2p_col,
    const int* __restrict__ pool_row,
    const __bf16* __restrict__ ws_bf,
    float* __restrict__ out) {
  // R12 = R11 (amortized 4-round staging + depth-2 gather prefetch) with
  // block-interleaved nf8 rows: gather is ONE 16B dwordx4 per pt per round
  // (was TWO 8B loads) -> vmem request count on the random-gather path
  // HALVES. Same bytes, same lines; targets the request-rate/queue-pressure
  // component of the congestion equilibrium.
  __shared__ __align__(16) char shbig[32768];   // [4][8192] W2 period buffer
  __bf16 (* const hs)[2][16][72] = (__bf16(*)[2][16][72])shbig; // epilogue union
  __shared__ __align__(16) __bf16 sbond[4][72];
  __shared__ __align__(16) float swdeg0[128][4];
  __shared__ float sbd0[128];
  __shared__ float sbias[64];
  __shared__ float sblin[64];
  __shared__ float sbd1[64];

  const int t = threadIdx.x;
  const int w = t >> 6;
  const int l = t & 63;
  const int m = l & 15;
  const int q = l >> 4;
  // block covers 128 p's: wave w gets [bid*128 + w*32, +32)
  const int pbase = blockIdx.x * 128 + w * 32;
  int pb[2]  = {pbase, pbase + 16};
  bool valid[2];
  int pbc[2];
  #pragma unroll
  for (int pt = 0; pt < 2; ++pt) {
    valid[pt] = pb[pt] < P_PERM;
    pbc[pt] = valid[pt] ? pb[pt] : (P_PERM - 16);
  }

  // ---- stage small LDS tables ----
  if (t < 256) sbond[t >> 6][t & 63] = (__bf16)bond_emb[t];
  if (t < 128) {
    *(float4*)&swdeg0[t][0] = *(const float4*)(w_deg0 + t * 4);
    sbd0[t] = b_deg0[t];
  } else if (t < 192) {
    int c = t - 128;
    sbias[c] = bias[c]; sblin[c] = b_lin[c]; sbd1[c] = b_deg1[c];
  }

  const unsigned char* __restrict__ nf8 = (const unsigned char*)ws_bf + NF8_OFF;
  const bf16x8* __restrict__ WLv  = (const bf16x8*)(ws_bf + WLF_OFF / 2);
  const bf16x8* __restrict__ WD1v = (const bf16x8*)(ws_bf + WD1F_OFF / 2);
  const unsigned* __restrict__ bep = (const unsigned*)((const char*)ws_bf + BE_OFF);
  const char* __restrict__ W2bytes = (const char*)ws_bf + W2F_OFF;

  // ---- wave-cooperative idx preloads: 1 KB per (array, pt) covers all 16 rounds ----
  intx4 nvx[2], evx[2], ncx[2];
  int bex[2];
  #pragma unroll
  for (int pt = 0; pt < 2; ++pt) {
    size_t rb = (size_t)pbc[pt] * 16;
    nvx[pt] = *(const intx4*)(n2p_val + rb + 4 * l);
    evx[pt] = *(const intx4*)(e2p_val + rb + 4 * l);
    ncx[pt] = *(const intx4*)(n2p_col + rb + 4 * l);
    bex[pt] = (int)bep[(size_t)pbc[pt] * 4 + l];
  }
  const int selbase = m * 16;  // byte selector base: src_lane = m*4 + (a>>2)

  // period staging: 4 chunks (32KB); wave w stages its quarter of each chunk
  auto stage4 = [&](int period) {
    #pragma unroll
    for (int c = 0; c < 4; ++c) {
      #pragma unroll
      for (int j = 0; j < 2; ++j) {
        const char* g = W2bytes + (size_t)(period * 4 + c) * 8192 +
                        (w * 2 + j) * 1024 + l * 16;
        char* lds = &shbig[c * 8192 + (w * 2 + j) * 1024];
        __builtin_amdgcn_global_load_lds(
            (const __attribute__((address_space(1))) unsigned*)g,
            (__attribute__((address_space(3))) unsigned*)lds, 16, 0, 0);
      }
    }
  };
  // gather one node row: ONE 16B load per pt (interleaved layout: bytes
  // [q*16, q*16+16) = blocks {q, q+4} = the lane's ks=0 and ks=1 fragments)
  auto gath = [&](int nc, uintx4* g) {
    if (BF16FEAT) {
      *g = *(const uintx4*)(nf8 + (size_t)nc * 64 + q * 16);
    } else {
      uintx4 o;
      {
        int k0 = q * 8;   // ks=0 elements
        float4 n0 = *(const float4*)(nfeat + (size_t)nc * 64 + k0);
        float4 n1 = *(const float4*)(nfeat + (size_t)nc * 64 + k0 + 4);
        o.x = pack_fp8x4(n0.x, n0.y, n0.z, n0.w);
        o.y = pack_fp8x4(n1.x, n1.y, n1.z, n1.w);
      }
      {
        int k0 = 32 + q * 8;  // ks=1 elements
        float4 n0 = *(const float4*)(nfeat + (size_t)nc * 64 + k0);
        float4 n1 = *(const float4*)(nfeat + (size_t)nc * 64 + k0 + 4);
        o.z = pack_fp8x4(n0.x, n0.y, n0.z, n0.w);
        o.w = pack_fp8x4(n1.x, n1.y, n1.z, n1.w);
      }
      *g = o;
    }
  };

  floatx4 acc[2][4] = {};
  float dsnv[2][4];
  int dsnc[2][4];
  // idx pipeline: cur (round a), nxt (a+1); a+2 computed in-round
  float nv0[2], ev0[2], nv1[2], ev1[2];
  int nc0[2], be0[2], nc1[2], be1[2];
  uintx4 g[3][2];  // 3-slot rotation: round a reads g[a%3], writes g[(a+2)%3]

  // prologue: idx+gathers for rounds 0 and 1; stage period 0
  #pragma unroll
  for (int pt = 0; pt < 2; ++pt) {
    nv0[pt] = __int_as_float(__builtin_amdgcn_ds_bpermute(selbase, nvx[pt][0]));
    ev0[pt] = __int_as_float(__builtin_amdgcn_ds_bpermute(selbase, evx[pt][0]));
    nc0[pt] = __builtin_amdgcn_ds_bpermute(selbase, ncx[pt][0]);
    be0[pt] = (__builtin_amdgcn_ds_bpermute(selbase, bex[pt])) & 0xff;
    gath(nc0[pt], &g[0][pt]);
    // round 1: sel = selbase + (1>>2)*4 = selbase, slot 1
    nv1[pt] = __int_as_float(__builtin_amdgcn_ds_bpermute(selbase, nvx[pt][1]));
    ev1[pt] = __int_as_float(__builtin_amdgcn_ds_bpermute(selbase, evx[pt][1]));
    nc1[pt] = __builtin_amdgcn_ds_bpermute(selbase, ncx[pt][1]);
    be1[pt] = (__builtin_amdgcn_ds_bpermute(selbase, bex[pt]) >> 8) & 0xff;
    gath(nc1[pt], &g[1][pt]);
  }
  stage4(0);
  __syncthreads();

  #pragma unroll
  for (int a = 0; a < 16; ++a) {
    const int sub = a & 3;       // chunk slot within the period buffer
    const int gcur = a % 3;
    const int gwr  = (a + 2) % 3;
    float nv2[2], ev2[2];
    int nc2[2], be2[2];
    if (a < 14) {
      const int an2 = a + 2;
      const int sel2 = selbase + (an2 >> 2) * 4;
      const int sl2 = an2 & 3;
      #pragma unroll
      for (int pt = 0; pt < 2; ++pt) {
        nv2[pt] = __int_as_float(__builtin_amdgcn_ds_bpermute(sel2, nvx[pt][sl2]));
        ev2[pt] = __int_as_float(__builtin_amdgcn_ds_bpermute(sel2, evx[pt][sl2]));
        nc2[pt] = __builtin_amdgcn_ds_bpermute(sel2, ncx[pt][sl2]);
        be2[pt] = (__builtin_amdgcn_ds_bpermute(sel2, bex[pt]) >> (sl2 * 8)) & 0xff;
      }
      #pragma unroll
      for (int pt = 0; pt < 2; ++pt) gath(nc2[pt], &g[gwr][pt]);
    }

    // compute round a (reads g[gcur], shbig[sub])
    bf16x8 afv[2][2];
    #pragma unroll
    for (int pt = 0; pt < 2; ++pt) {
      uintx4 gv = g[gcur][pt];
      #pragma unroll
      for (int ks = 0; ks < 2; ++ks) {
        bf16x8 eb = *(const bf16x8*)&sbond[be0[pt]][ks * 32 + q * 8];
        unsigned w0 = gv[ks * 2];
        unsigned w1 = gv[ks * 2 + 1];
        floatx2 x01 = unpk_fp8_lo(w0);
        floatx2 x23 = unpk_fp8_hi(w0);
        floatx2 x45 = unpk_fp8_lo(w1);
        floatx2 x67 = unpk_fp8_hi(w1);
        float xs[8] = {x01.x, x01.y, x23.x, x23.y, x45.x, x45.y, x67.x, x67.y};
        bf16x8 af;
        #pragma unroll
        for (int j = 0; j < 8; ++j)
          af[j] = (__bf16)fmaf(nv0[pt], xs[j], ev0[pt] * (float)eb[j]);
        afv[pt][ks] = af;
      }
    }
    #pragma unroll
    for (int ks = 0; ks < 2; ++ks)
      #pragma unroll
      for (int ct = 0; ct < 4; ++ct) {
        bf16x8 frag = *(const bf16x8*)&shbig[sub * 8192 + ((ks * 4 + ct) * 64 + l) * 16];
        acc[0][ct] = __builtin_amdgcn_mfma_f32_16x16x32_bf16(afv[0][ks], frag, acc[0][ct], 0, 0, 0);
        acc[1][ct] = __builtin_amdgcn_mfma_f32_16x16x32_bf16(afv[1][ks], frag, acc[1][ct], 0, 0, 0);
      }

    // deg_sel fold at a = 0,5,10,15: record nv/node; random degs load DEFERRED
    if (a == 0 || a == 5 || a == 10 || a == 15) {
      const int jj = a / 5;
      #pragma unroll
      for (int pt = 0; pt < 2; ++pt) {
        dsnv[pt][jj] = nv0[pt];
        dsnc[pt][jj] = nc0[pt];
      }
    }

    // period boundary: refill the 32KB buffer (only 3x per block). Register
    // gathers (wave-private) are drained here but never corrupted.
    if (a < 15 && sub == 3) {
      __syncthreads();           // all waves done reading this period's chunks
      stage4((a + 1) >> 2);
      __syncthreads();           // staging landed (vmcnt(0) implied)
    }

    if (a < 15) {
      #pragma unroll
      for (int pt = 0; pt < 2; ++pt) {
        nv0[pt] = nv1[pt]; ev0[pt] = ev1[pt]; nc0[pt] = nc1[pt]; be0[pt] = be1[pt];
      }
    }
    if (a < 14) {
      #pragma unroll
      for (int pt = 0; pt < 2; ++pt) {
        nv1[pt] = nv2[pt]; ev1[pt] = ev2[pt]; nc1[pt] = nc2[pt]; be1[pt] = be2[pt];
      }
    }
  }

  // deferred deg gathers: 8 independent random loads; first use is the g-MLP,
  // so latency overlaps the hs/acc2 section below.
  float dsreg[2][4];
  #pragma unroll
  for (int pt = 0; pt < 2; ++pt)
    #pragma unroll
    for (int jj = 0; jj < 4; ++jj)
      dsreg[pt][jj] = dsnv[pt][jj] * degs[dsnc[pt][jj]];

  // W2 reads of round 15 must complete in ALL waves before hs (union'd in
  // shbig) is written.
  __syncthreads();

  // ---- hr = relu(acc + bias) -> LDS (A-frag layout) -> @ w_lin^T ----
  floatx4 acc2[2][4] = {};
  {
    #pragma unroll
    for (int pt = 0; pt < 2; ++pt)
      #pragma unroll
      for (int ct = 0; ct < 4; ++ct) {
        float bv = sbias[ct * 16 + m];
        #pragma unroll
        for (int rr = 0; rr < 4; ++rr)
          hs[w][pt][q * 4 + rr][ct * 16 + m] =
              (__bf16)fmaxf(acc[pt][ct][rr] + bv, 0.0f);
      }
    #pragma unroll
    for (int pt = 0; pt < 2; ++pt)
      #pragma unroll
      for (int ks = 0; ks < 2; ++ks) {
        bf16x8 af2 = *(const bf16x8*)&hs[w][pt][m][ks * 32 + q * 8];
        #pragma unroll
        for (int ct = 0; ct < 4; ++ct) {
          bf16x8 frag = WLv[(ks * 4 + ct) * 64 + l];
          acc2[pt][ct] = __builtin_amdgcn_mfma_f32_16x16x32_bf16(af2, frag, acc2[pt][ct], 0, 0, 0);
        }
      }
  }

  // ---- g-MLP (w_deg0/b_deg0 from LDS) ----
  floatx4 gacc[2][4] = {};
  #pragma unroll
  for (int ks = 0; ks < 4; ++ks) {
    const int k0 = ks * 32 + q * 8;
    bf16x8 af[2];
    #pragma unroll
    for (int j = 0; j < 8; ++j) {
      int k = k0 + j;
      float4 wr = *(const float4*)&swdeg0[k][0];
      float bk = sbd0[k];
      #pragma unroll
      for (int pt = 0; pt < 2; ++pt) {
        float v = bk;
        v = fmaf(dsreg[pt][0], wr.x, v);
        v = fmaf(dsreg[pt][1], wr.y, v);
        v = fmaf(dsreg[pt][2], wr.z, v);
        v = fmaf(dsreg[pt][3], wr.w, v);
        af[pt][j] = (__bf16)fmaxf(v, 0.0f);
      }
    }
    #pragma unroll
    for (int ct = 0; ct < 4; ++ct) {
      bf16x8 frag = WD1v[(ks * 4 + ct) * 64 + l];
      gacc[0][ct] = __builtin_amdgcn_mfma_f32_16x16x32_bf16(af[0], frag, gacc[0][ct], 0, 0, 0);
      gacc[1][ct] = __builtin_amdgcn_mfma_f32_16x16x32_bf16(af[1], frag, gacc[1][ct], 0, 0, 0);
    }
  }

  // ---- h2 = (acc2 + b_lin) * (gacc + b_deg1); pooled scatter ----
  #pragma unroll
  for (int pt = 0; pt < 2; ++pt) {
    if (!valid[pt]) continue;
    intx4   pr4 = *(const intx4*)(pool_row + pb[pt] + q * 4);
    floatx4 pv4 = *(const floatx4*)(pool_val + pb[pt] + q * 4);
    #pragma unroll
    for (int rr = 0; rr < 4; ++rr) {
      float* orow = out + (size_t)pr4[rr] * 64;
      float pv = pv4[rr];
      #pragma unroll
      for (int ct = 0; ct < 4; ++ct) {
        float h2 = (acc2[pt][ct][rr] + sblin[ct * 16 + m]) *
                   (gacc[pt][ct][rr] + sbd1[ct * 16 + m]);
        atomicAdd(orow + ct * 16 + m, pv * h2);
      }
    }
  }
}

extern "C" void kernel_launch(void* const* d_in, const int* in_sizes, int n_in,
                              void* d_out, int out_size, void* d_ws, size_t ws_size,
                              hipStream_t stream) {
  const float* nfeat    = (const float*)d_in[0];
  const float* degs     = (const float*)d_in[1];
  const float* n2p_val  = (const float*)d_in[2];
  const float* e2p_val  = (const float*)d_in[3];
  const float* pool_val = (const float*)d_in[4];
  const float* weights  = (const float*)d_in[5];
  const float* bias     = (const float*)d_in[6];
  const float* w_deg0   = (const float*)d_in[7];
  const float* b_deg0   = (const float*)d_in[8];
  const float* w_deg1   = (const float*)d_in[9];
  const float* b_deg1   = (const float*)d_in[10];
  const float* w_lin    = (const float*)d_in[11];
  const float* b_lin    = (const float*)d_in[12];
  const float* bond_emb = (const float*)d_in[13];
  const int* edge_feat_idx = (const int*)d_in[14];
  const int* n2p_col    = (const int*)d_in[16];
  const int* e2p_col    = (const int*)d_in[18];
  const int* pool_row   = (const int*)d_in[19];

  float* out = (float*)d_out;
  __bf16* ws_bf = (__bf16*)d_ws;

  prep_all_kernel<<<12804, 256, 0, stream>>>((float4*)out, weights, w_lin,
                                             w_deg1, nfeat, e2p_col,
                                             edge_feat_idx, ws_bf);

  int grid = (P_PERM + 127) / 128;  // 1563
  if (ws_size >= WS_NEED_FULL) {
    lrp_mfma_kernel<true><<<grid, 256, 0, stream>>>(
        nfeat, degs, n2p_val, e2p_val, pool_val, bias, w_deg0, b_deg0,
        b_deg1, b_lin, bond_emb, n2p_col, pool_row, ws_bf, out);
  } else {
    lrp_mfma_kernel<false><<<grid, 256, 0, stream>>>(
        nfeat, degs, n2p_val, e2p_val, pool_val, bias, w_deg0, b_deg0,
        b_deg1, b_lin, bond_emb, n2p_col, pool_row, ws_bf, out);
  }
}